// Round 10
// baseline (85.279 us; speedup 1.0000x reference)
//
#include <hip/hip_runtime.h>

// Problem constants (B=4, N=M=8192, D=3)
#define NPTS   8192
#define BATCH  4
#define MSPLIT 16                // m-range splits per (b,dir)
#define QB     8                 // query tiles (32 queries each) per wave
#define TILES  (NPTS / 32)       // 256 point-tiles per (cloud,b)
#define TPB    (TILES / MSPLIT)  // 16 db tiles per wave
#define ITER   TPB               // one tile per inner iteration
#define NQTOT  (BATCH * 2 * NPTS)
#define NWAVES (32 * 8 * MSPLIT) // 4096 logical waves (32 qw * 8 bd * MSPLIT)
#define WPB    4                 // waves per workgroup

typedef _Float16 f16x8  __attribute__((ext_vector_type(8)));
typedef float    f32x16 __attribute__((ext_vector_type(16)));

// ws layout (bytes):
//   TA  [8 bd][256 tile][64 lane] f16x8   @ 0      (2 MB)  db-role frags
//   QF  [8 bd][256 tile][64 lane] f16x8   @ 2 MB   (2 MB)  query-role frags
//   H   [8 bd][8192] fp32                 @ 4 MB   (256 KB) |p|^2 exact
//   MIN [MSPLIT][8 bd][8192] fp32         @ 4.25 MB (4 MB) partial mins
#define TA_OFF  ((size_t)0)
#define QF_OFF  ((size_t)2 << 20)
#define H_OFF   ((size_t)4 << 20)
#define MIN_OFF (((size_t)4 << 20) + ((size_t)256 << 10))

// ---- Prepack: hi/lo f16 split K-vectors in MFMA lane order (K=16).
// A (db)    k = [th.x th.y th.z  th.x th.y th.z  tl.x tl.y | tl.z tl.x tl.y tl.z  hth htl 0 0]
// B (query) k = [rh.x rh.y rh.z  rl.x rl.y rl.z  rh.x rh.y | rh.z rl.x rl.y rl.z  1   1   0 0]
// (r = -2q). Dot = rh·th + rl·th + rh·tl + rl·tl + hth + htl ≈ ht - 2 q·t.
__global__ __launch_bounds__(256) void chamfer_prepack(
    const float* __restrict__ src, const float* __restrict__ tgt,
    f16x8* __restrict__ TA, f16x8* __restrict__ QF, float* __restrict__ H,
    float* __restrict__ out)
{
    int tid = blockIdx.x * 256 + threadIdx.x;      // (c*4+b)*8192 + pt
    if (tid == 0) out[0] = 0.0f;                   // replaces memset dispatch
    int c   = tid >> 15;
    int r   = tid & 32767;                         // b*8192 + pt
    const float* p = (c ? tgt : src) + (size_t)r * 3;
    float x = p[0], y = p[1], z = p[2];
    float h = x * x + y * y + z * z;
    H[tid] = h;

    _Float16 thx = (_Float16)x, thy = (_Float16)y, thz = (_Float16)z;
    _Float16 tlx = (_Float16)(x - (float)thx);
    _Float16 tly = (_Float16)(y - (float)thy);
    _Float16 tlz = (_Float16)(z - (float)thz);
    _Float16 hh  = (_Float16)h;
    _Float16 hl  = (_Float16)(h - (float)hh);

    float rx = -2.f * x, ry = -2.f * y, rz = -2.f * z;
    _Float16 rhx = (_Float16)rx, rhy = (_Float16)ry, rhz = (_Float16)rz;
    _Float16 rlx = (_Float16)(rx - (float)rhx);
    _Float16 rly = (_Float16)(ry - (float)rhy);
    _Float16 rlz = (_Float16)(rz - (float)rhz);

    int pt   = r & 8191;
    int bd   = tid >> 13;                          // c*4+b
    int tile = pt >> 5, ln = pt & 31;
    size_t base = ((size_t)bd * TILES + tile) * 64;

    _Float16 z0 = (_Float16)0.f, one = (_Float16)1.f;
    f16x8 alo = {thx, thy, thz, thx, thy, thz, tlx, tly};
    f16x8 ahi = {tlz, tlx, tly, tlz, hh,  hl,  z0,  z0 };
    TA[base + ln]      = alo;
    TA[base + 32 + ln] = ahi;
    f16x8 blo = {rhx, rhy, rhz, rlx, rly, rlz, rhx, rhy};
    f16x8 bhi = {rhz, rlx, rly, rlz, one, one, z0,  z0 };
    QF[base + ln]      = blo;
    QF[base + 32 + ln] = bhi;
}

// min3 tree over the 16 C regs (rows = 16 of 32 db points; other half in lane^32)
__device__ __forceinline__ float red16(const f32x16& d) {
    float a = fminf(fminf(d[0],  d[1]),  d[2]);
    float b = fminf(fminf(d[3],  d[4]),  d[5]);
    float c = fminf(fminf(d[6],  d[7]),  d[8]);
    float e = fminf(fminf(d[9],  d[10]), d[11]);
    float f = fminf(fminf(d[12], d[13]), d[14]);
    float g = fminf(fminf(a, b), d[15]);
    float h = fminf(fminf(c, e), f);
    return fminf(g, h);
}

// ---- Main: WPB=4 independent waves per 256-thread block.
// grid = NWAVES/WPB = 1024 blocks -> 4 blocks/CU -> 16 waves/CU (4/SIMD).
// QB=8: 8 independent MFMAs per db tile (ILP) + half the TA L2 re-reads.
// wid decode: [4:0]=qw (8 query tiles each), [7:5]=bd, [11:8]=ms
__global__ __launch_bounds__(256, 4) void chamfer_main(
    const f16x8* __restrict__ TA, const f16x8* __restrict__ QF,
    float* __restrict__ minarr)
{
    const int wid  = blockIdx.x * WPB + (threadIdx.x >> 6);
    const int lane = threadIdx.x & 63;
    const int qw   = wid & 31;
    const int bd   = (wid >> 5) & 7;     // dir*4+b (queries from cloud=dir)
    const int ms   = wid >> 8;           // 0..MSPLIT-1
    const int bdT  = bd ^ 4;             // db side = opposite cloud

    f16x8 qf[QB];
    size_t qbase = ((size_t)bd * TILES + qw * QB) * 64 + lane;
    #pragma unroll
    for (int t = 0; t < QB; ++t) qf[t] = QF[qbase + t * 64];

    const f32x16 zero = {0.f,0.f,0.f,0.f,0.f,0.f,0.f,0.f,
                         0.f,0.f,0.f,0.f,0.f,0.f,0.f,0.f};
    float mn[QB];
    #pragma unroll
    for (int t = 0; t < QB; ++t) mn[t] = 3.0e38f;

    const size_t tbase = ((size_t)bdT * TILES + ms * TPB) * 64 + lane;

    // Software-pipelined: prefetch next db tile while computing current.
    f16x8 a = TA[tbase];
    for (int i = 0; i < ITER - 1; ++i) {
        f16x8 n = TA[tbase + (size_t)(i + 1) * 64];
        #pragma unroll
        for (int t = 0; t < QB; ++t) {
            f32x16 d = __builtin_amdgcn_mfma_f32_32x32x16_f16(a, qf[t], zero, 0, 0, 0);
            mn[t] = fminf(mn[t], red16(d));
        }
        a = n;
    }
    #pragma unroll
    for (int t = 0; t < QB; ++t) {
        f32x16 d = __builtin_amdgcn_mfma_f32_32x32x16_f16(a, qf[t], zero, 0, 0, 0);
        mn[t] = fminf(mn[t], red16(d));
    }

    // Each lane covered 16 of 32 rows per tile; other 16 rows in lane^32.
    #pragma unroll
    for (int t = 0; t < QB; ++t) mn[t] = fminf(mn[t], __shfl_xor(mn[t], 32));

    // Both wave halves store: lanes<32 write t=0..3, lanes>=32 write t=4..7.
    {
        const int half = lane >> 5, col = lane & 31;
        float* base = minarr + (size_t)ms * NQTOT + (size_t)bd * NPTS
                    + qw * (QB * 32) + half * (4 * 32) + col;
        #pragma unroll
        for (int t = 0; t < 4; ++t) base[t * 32] = mn[t + 4 * half];
    }
}

// ---- Reduce: min over MSPLIT partials, + |q|^2, sum, scale ----
__global__ __launch_bounds__(256) void chamfer_reduce(
    const float* __restrict__ minarr, const float* __restrict__ H,
    float* __restrict__ out)
{
    const int q = blockIdx.x * 256 + threadIdx.x;   // bd*8192 + n
    float m = 3.4e38f;
    #pragma unroll
    for (int ms = 0; ms < MSPLIT; ++ms)
        m = fminf(m, minarr[(size_t)ms * NQTOT + q]);
    float acc = m + H[q];
    #pragma unroll
    for (int off = 32; off > 0; off >>= 1) acc += __shfl_down(acc, off);

    __shared__ float sdata[4];
    if ((threadIdx.x & 63) == 0) sdata[threadIdx.x >> 6] = acc;
    __syncthreads();
    if (threadIdx.x == 0) {
        float t = (sdata[0] + sdata[1]) + (sdata[2] + sdata[3]);
        atomicAdd(out, t * (1.0f / (float)(BATCH * NPTS)));
    }
}

extern "C" void kernel_launch(void* const* d_in, const int* in_sizes, int n_in,
                              void* d_out, int out_size, void* d_ws, size_t ws_size,
                              hipStream_t stream) {
    const float* src = (const float*)d_in[0];   // (B, N, 3) fp32
    const float* tgt = (const float*)d_in[1];   // (B, M, 3) fp32
    float* out = (float*)d_out;

    f16x8* TA     = (f16x8*)((char*)d_ws + TA_OFF);
    f16x8* QF     = (f16x8*)((char*)d_ws + QF_OFF);
    float* H      = (float*)((char*)d_ws + H_OFF);
    float* minarr = (float*)((char*)d_ws + MIN_OFF);

    chamfer_prepack<<<NQTOT / 256, 256, 0, stream>>>(src, tgt, TA, QF, H, out);
    chamfer_main<<<NWAVES / WPB, 256, 0, stream>>>(TA, QF, minarr);
    chamfer_reduce<<<NQTOT / 256, 256, 0, stream>>>(minarr, H, out);
}

// Round 11
// 83.537 us; speedup vs baseline: 1.0209x; 1.0209x over previous
//
#include <hip/hip_runtime.h>

// Problem constants (B=4, N=M=8192, D=3)
#define NPTS   8192
#define BATCH  4
#define MSPLIT 16                // m-range splits per (b,dir)
#define QB     4                 // query tiles (32 queries each) per wave
#define TILES  (NPTS / 32)       // 256 point-tiles per (cloud,b)
#define TPB    (TILES / MSPLIT)  // 16 db tiles per wave
#define ITER   TPB               // one tile per inner iteration
#define NQTOT  (BATCH * 2 * NPTS)
#define NWAVES (64 * 8 * MSPLIT) // 8192 logical waves (64 qw * 8 bd * MSPLIT)
#define WPB    4                 // waves per workgroup

typedef _Float16 f16x8  __attribute__((ext_vector_type(8)));
typedef float    f32x16 __attribute__((ext_vector_type(16)));

// ws layout (bytes):
//   TA  [8 bd][256 tile][64 lane] f16x8   @ 0      (2 MB)  db-role frags
//   QF  [8 bd][256 tile][64 lane] f16x8   @ 2 MB   (2 MB)  query-role frags
//   H   [8 bd][8192] fp32                 @ 4 MB   (256 KB) |p|^2 exact
//   MIN [MSPLIT][8 bd][8192] fp32         @ 4.25 MB (4 MB) partial mins
#define TA_OFF  ((size_t)0)
#define QF_OFF  ((size_t)2 << 20)
#define H_OFF   ((size_t)4 << 20)
#define MIN_OFF (((size_t)4 << 20) + ((size_t)256 << 10))

// ---- Prepack: hi/lo f16 split K-vectors in MFMA lane order (K=16).
// A (db)    k = [th.x th.y th.z  th.x th.y th.z  tl.x tl.y | tl.z tl.x tl.y tl.z  hth htl 0 0]
// B (query) k = [rh.x rh.y rh.z  rl.x rl.y rl.z  rh.x rh.y | rh.z rl.x rl.y rl.z  1   1   0 0]
// (r = -2q). Dot = rh·th + rl·th + rh·tl + rl·tl + hth + htl ≈ ht - 2 q·t.
__global__ __launch_bounds__(256) void chamfer_prepack(
    const float* __restrict__ src, const float* __restrict__ tgt,
    f16x8* __restrict__ TA, f16x8* __restrict__ QF, float* __restrict__ H,
    float* __restrict__ out)
{
    int tid = blockIdx.x * 256 + threadIdx.x;      // (c*4+b)*8192 + pt
    if (tid == 0) out[0] = 0.0f;                   // replaces memset dispatch
    int c   = tid >> 15;
    int r   = tid & 32767;                         // b*8192 + pt
    const float* p = (c ? tgt : src) + (size_t)r * 3;
    float x = p[0], y = p[1], z = p[2];
    float h = x * x + y * y + z * z;
    H[tid] = h;

    _Float16 thx = (_Float16)x, thy = (_Float16)y, thz = (_Float16)z;
    _Float16 tlx = (_Float16)(x - (float)thx);
    _Float16 tly = (_Float16)(y - (float)thy);
    _Float16 tlz = (_Float16)(z - (float)thz);
    _Float16 hh  = (_Float16)h;
    _Float16 hl  = (_Float16)(h - (float)hh);

    float rx = -2.f * x, ry = -2.f * y, rz = -2.f * z;
    _Float16 rhx = (_Float16)rx, rhy = (_Float16)ry, rhz = (_Float16)rz;
    _Float16 rlx = (_Float16)(rx - (float)rhx);
    _Float16 rly = (_Float16)(ry - (float)rhy);
    _Float16 rlz = (_Float16)(rz - (float)rhz);

    int pt   = r & 8191;
    int bd   = tid >> 13;                          // c*4+b
    int tile = pt >> 5, ln = pt & 31;
    size_t base = ((size_t)bd * TILES + tile) * 64;

    _Float16 z0 = (_Float16)0.f, one = (_Float16)1.f;
    f16x8 alo = {thx, thy, thz, thx, thy, thz, tlx, tly};
    f16x8 ahi = {tlz, tlx, tly, tlz, hh,  hl,  z0,  z0 };
    TA[base + ln]      = alo;
    TA[base + 32 + ln] = ahi;
    f16x8 blo = {rhx, rhy, rhz, rlx, rly, rlz, rhx, rhy};
    f16x8 bhi = {rhz, rlx, rly, rlz, one, one, z0,  z0 };
    QF[base + ln]      = blo;
    QF[base + 32 + ln] = bhi;
}

// min over 16 C regs fused with running min (v_min3 chain, 9 instrs)
__device__ __forceinline__ float red16_acc(const f32x16& d, float mn) {
    float a = fminf(fminf(d[0],  d[1]),  d[2]);
    float b = fminf(fminf(d[3],  d[4]),  d[5]);
    float c = fminf(fminf(d[6],  d[7]),  d[8]);
    float e = fminf(fminf(d[9],  d[10]), d[11]);
    float f = fminf(fminf(d[12], d[13]), d[14]);
    float g = fminf(fminf(a, b), d[15]);
    float h = fminf(fminf(c, e), f);
    return fminf(fminf(mn, g), h);
}

// ---- Main: WPB=4 waves per 256-thread block; the 4 waves share (bd,ms) and
// consecutive qw -> identical TA streams (L1-served after first wave).
// grid = NWAVES/WPB = 2048 blocks -> 8 blocks/CU -> 32 waves/CU (8/SIMD).
// Depth-2 tile prefetch hides ~200cyc L2 latency under 2 tiles of MFMA issue.
// wid decode: [5:0]=qw, [8:6]=bd, [12:9]=ms
__global__ __launch_bounds__(256, 8) void chamfer_main(
    const f16x8* __restrict__ TA, const f16x8* __restrict__ QF,
    float* __restrict__ minarr)
{
    const int wid  = blockIdx.x * WPB + (threadIdx.x >> 6);
    const int lane = threadIdx.x & 63;
    const int qw   = wid & 63;
    const int bd   = (wid >> 6) & 7;     // dir*4+b (queries from cloud=dir)
    const int ms   = wid >> 9;           // 0..MSPLIT-1
    const int bdT  = bd ^ 4;             // db side = opposite cloud

    f16x8 qf[QB];
    size_t qbase = ((size_t)bd * TILES + qw * QB) * 64 + lane;
    #pragma unroll
    for (int t = 0; t < QB; ++t) qf[t] = QF[qbase + t * 64];

    const f32x16 zero = {0.f,0.f,0.f,0.f,0.f,0.f,0.f,0.f,
                         0.f,0.f,0.f,0.f,0.f,0.f,0.f,0.f};
    float mn[QB];
    #pragma unroll
    for (int t = 0; t < QB; ++t) mn[t] = 3.0e38f;

    const size_t tbase = ((size_t)bdT * TILES + ms * TPB) * 64 + lane;

    // Depth-2 software pipeline: two db tiles in flight.
    f16x8 a  = TA[tbase];
    f16x8 n0 = TA[tbase + 64];
    for (int i = 0; i < ITER - 2; ++i) {
        f16x8 n1 = TA[tbase + (size_t)(i + 2) * 64];
        #pragma unroll
        for (int t = 0; t < QB; ++t) {
            f32x16 d = __builtin_amdgcn_mfma_f32_32x32x16_f16(a, qf[t], zero, 0, 0, 0);
            mn[t] = red16_acc(d, mn[t]);
        }
        a = n0; n0 = n1;
    }
    #pragma unroll
    for (int j = 0; j < 2; ++j) {
        #pragma unroll
        for (int t = 0; t < QB; ++t) {
            f32x16 d = __builtin_amdgcn_mfma_f32_32x32x16_f16(a, qf[t], zero, 0, 0, 0);
            mn[t] = red16_acc(d, mn[t]);
        }
        a = n0;
    }

    // Each lane covered 16 of 32 rows per tile; other 16 rows in lane^32.
    #pragma unroll
    for (int t = 0; t < QB; ++t) mn[t] = fminf(mn[t], __shfl_xor(mn[t], 32));

    // Lanes<32 store t=0,1; lanes>=32 store t=2,3 (both halves write).
    {
        const int half = lane >> 5, col = lane & 31;
        float* base = minarr + (size_t)ms * NQTOT + (size_t)bd * NPTS
                    + qw * (QB * 32) + half * (2 * 32) + col;
        #pragma unroll
        for (int t = 0; t < 2; ++t) base[t * 32] = mn[t + 2 * half];
    }
}

// ---- Reduce: min over MSPLIT partials, + |q|^2, sum, scale ----
__global__ __launch_bounds__(256) void chamfer_reduce(
    const float* __restrict__ minarr, const float* __restrict__ H,
    float* __restrict__ out)
{
    const int q = blockIdx.x * 256 + threadIdx.x;   // bd*8192 + n
    float m = 3.4e38f;
    #pragma unroll
    for (int ms = 0; ms < MSPLIT; ++ms)
        m = fminf(m, minarr[(size_t)ms * NQTOT + q]);
    float acc = m + H[q];
    #pragma unroll
    for (int off = 32; off > 0; off >>= 1) acc += __shfl_down(acc, off);

    __shared__ float sdata[4];
    if ((threadIdx.x & 63) == 0) sdata[threadIdx.x >> 6] = acc;
    __syncthreads();
    if (threadIdx.x == 0) {
        float t = (sdata[0] + sdata[1]) + (sdata[2] + sdata[3]);
        atomicAdd(out, t * (1.0f / (float)(BATCH * NPTS)));
    }
}

extern "C" void kernel_launch(void* const* d_in, const int* in_sizes, int n_in,
                              void* d_out, int out_size, void* d_ws, size_t ws_size,
                              hipStream_t stream) {
    const float* src = (const float*)d_in[0];   // (B, N, 3) fp32
    const float* tgt = (const float*)d_in[1];   // (B, M, 3) fp32
    float* out = (float*)d_out;

    f16x8* TA     = (f16x8*)((char*)d_ws + TA_OFF);
    f16x8* QF     = (f16x8*)((char*)d_ws + QF_OFF);
    float* H      = (float*)((char*)d_ws + H_OFF);
    float* minarr = (float*)((char*)d_ws + MIN_OFF);

    chamfer_prepack<<<NQTOT / 256, 256, 0, stream>>>(src, tgt, TA, QF, H, out);
    chamfer_main<<<NWAVES / WPB, 256, 0, stream>>>(TA, QF, minarr);
    chamfer_reduce<<<NQTOT / 256, 256, 0, stream>>>(minarr, H, out);
}